// Round 2
// baseline (339.335 us; speedup 1.0000x reference)
//
#include <hip/hip_runtime.h>

// MatrixFactorization: out[i] = dot(user_i, item_table[dest_i])
// user_i = b + sum_k emb_k[idx_k[i]] @ W_k  (W_k = rows [4k,4k+4) of W[24,32])
// Round 2: 4 rows/thread (int4 index loads, 4 independent item-gather chains),
// __launch_bounds__(256,4) to cap VGPR<=128 -> 4 waves/SIMD.

#define NF 32
#define LDS_STRIDE 36           // floats per padded table row (144 B, 16B-aligned)
#define NV 176                  // 7+24+2+100+12+31 vocab entries

__device__ __forceinline__ float4 ldsf4(const float* p) {
    return *reinterpret_cast<const float4*>(p);
}

// acc += dot( sum of 6 LDS user quads , item quad )
#define USER_DOT(ACC, IV, B0, B1, B2, B3, B4, B5)                         \
    {                                                                     \
        float4 u0 = ldsf4(&proj[(B0) + q * 4]);                           \
        float4 u1 = ldsf4(&proj[(B1) + q * 4]);                           \
        float4 u2 = ldsf4(&proj[(B2) + q * 4]);                           \
        float4 u3 = ldsf4(&proj[(B3) + q * 4]);                           \
        float4 u4 = ldsf4(&proj[(B4) + q * 4]);                           \
        float4 u5 = ldsf4(&proj[(B5) + q * 4]);                           \
        float ux = u0.x + u1.x + u2.x + u3.x + u4.x + u5.x;               \
        float uy = u0.y + u1.y + u2.y + u3.y + u4.y + u5.y;               \
        float uz = u0.z + u1.z + u2.z + u3.z + u4.z + u5.z;               \
        float uw = u0.w + u1.w + u2.w + u3.w + u4.w + u5.w;               \
        ACC = fmaf(ux, (IV).x, ACC);                                      \
        ACC = fmaf(uy, (IV).y, ACC);                                      \
        ACC = fmaf(uz, (IV).z, ACC);                                      \
        ACC = fmaf(uw, (IV).w, ACC);                                      \
    }

__global__ __launch_bounds__(256, 4)
void mf_kernel(const int* __restrict__ dow, const int* __restrict__ tmi,
               const int* __restrict__ sx,  const int* __restrict__ ag,
               const int* __restrict__ mo,  const int* __restrict__ dy,
               const int* __restrict__ dst,
               const float* __restrict__ e_dow,   const float* __restrict__ e_time,
               const float* __restrict__ e_sex,   const float* __restrict__ e_age,
               const float* __restrict__ e_month, const float* __restrict__ e_day,
               const float* __restrict__ W, const float* __restrict__ bvec,
               const float* __restrict__ item_table,
               float* __restrict__ out, int n)
{
    __shared__ float proj[NV * LDS_STRIDE];   // 25,344 B

    // ---- Stage 1: build projected vocab tables in LDS ----
    const int tid = threadIdx.x;
    for (int t = tid; t < NV * NF; t += blockDim.x) {
        int entry = t >> 5;
        int f     = t & 31;
        int k, v;
        const float* e;
        if      (entry < 7)   { k = 0; v = entry;       e = e_dow;   }
        else if (entry < 31)  { k = 1; v = entry - 7;   e = e_time;  }
        else if (entry < 33)  { k = 2; v = entry - 31;  e = e_sex;   }
        else if (entry < 133) { k = 3; v = entry - 33;  e = e_age;   }
        else if (entry < 145) { k = 4; v = entry - 133; e = e_month; }
        else                  { k = 5; v = entry - 145; e = e_day;   }
        float acc = (k == 0) ? bvec[f] : 0.0f;
        #pragma unroll
        for (int d = 0; d < 4; ++d)
            acc += e[v * 4 + d] * W[(k * 4 + d) * NF + f];
        proj[entry * LDS_STRIDE + f] = acc;
    }
    __syncthreads();

    // ---- Stage 2: 4 rows per thread ----
    const int nquad = n >> 2;
    const int tstride = gridDim.x * blockDim.x;
    for (int t = blockIdx.x * blockDim.x + tid; t < nquad; t += tstride) {
        const int4 i0 = reinterpret_cast<const int4*>(dow)[t];
        const int4 i1 = reinterpret_cast<const int4*>(tmi)[t];
        const int4 i2 = reinterpret_cast<const int4*>(sx)[t];
        const int4 i3 = reinterpret_cast<const int4*>(ag)[t];
        const int4 i4 = reinterpret_cast<const int4*>(mo)[t];
        const int4 i5 = reinterpret_cast<const int4*>(dy)[t];
        const int4 id = reinterpret_cast<const int4*>(dst)[t];

        // LDS row bases (floats) for each of 4 rows x 6 features
        const int a0 = (0   + i0.x) * LDS_STRIDE, b0 = (0   + i0.y) * LDS_STRIDE,
                  c0 = (0   + i0.z) * LDS_STRIDE, d0 = (0   + i0.w) * LDS_STRIDE;
        const int a1 = (7   + i1.x) * LDS_STRIDE, b1 = (7   + i1.y) * LDS_STRIDE,
                  c1 = (7   + i1.z) * LDS_STRIDE, d1 = (7   + i1.w) * LDS_STRIDE;
        const int a2 = (31  + i2.x) * LDS_STRIDE, b2 = (31  + i2.y) * LDS_STRIDE,
                  c2 = (31  + i2.z) * LDS_STRIDE, d2 = (31  + i2.w) * LDS_STRIDE;
        const int a3 = (33  + i3.x) * LDS_STRIDE, b3 = (33  + i3.y) * LDS_STRIDE,
                  c3 = (33  + i3.z) * LDS_STRIDE, d3 = (33  + i3.w) * LDS_STRIDE;
        const int a4 = (133 + i4.x) * LDS_STRIDE, b4 = (133 + i4.y) * LDS_STRIDE,
                  c4 = (133 + i4.z) * LDS_STRIDE, d4 = (133 + i4.w) * LDS_STRIDE;
        const int a5 = (145 + i5.x) * LDS_STRIDE, b5 = (145 + i5.y) * LDS_STRIDE,
                  c5 = (145 + i5.z) * LDS_STRIDE, d5 = (145 + i5.w) * LDS_STRIDE;

        const float4* itA = reinterpret_cast<const float4*>(item_table + (long long)id.x * NF);
        const float4* itB = reinterpret_cast<const float4*>(item_table + (long long)id.y * NF);
        const float4* itC = reinterpret_cast<const float4*>(item_table + (long long)id.z * NF);
        const float4* itD = reinterpret_cast<const float4*>(item_table + (long long)id.w * NF);

        float accA = 0.0f, accB = 0.0f, accC = 0.0f, accD = 0.0f;
        #pragma unroll
        for (int q = 0; q < 8; ++q) {
            float4 ivA = itA[q];
            float4 ivB = itB[q];
            float4 ivC = itC[q];
            float4 ivD = itD[q];
            USER_DOT(accA, ivA, a0, a1, a2, a3, a4, a5);
            USER_DOT(accB, ivB, b0, b1, b2, b3, b4, b5);
            USER_DOT(accC, ivC, c0, c1, c2, c3, c4, c5);
            USER_DOT(accD, ivD, d0, d1, d2, d3, d4, d5);
        }
        float4 o; o.x = accA; o.y = accB; o.z = accC; o.w = accD;
        reinterpret_cast<float4*>(out)[t] = o;
    }

    // tail (n not divisible by 4) — not taken for N=2M, kept for correctness
    const int tail_start = (n >> 2) << 2;
    const int gtid = blockIdx.x * blockDim.x + tid;
    for (int i = tail_start + gtid; i < n; i += tstride) {
        const int t0 = (0   + dow[i]) * LDS_STRIDE;
        const int t1 = (7   + tmi[i]) * LDS_STRIDE;
        const int t2 = (31  + sx[i])  * LDS_STRIDE;
        const int t3 = (33  + ag[i])  * LDS_STRIDE;
        const int t4 = (133 + mo[i])  * LDS_STRIDE;
        const int t5 = (145 + dy[i])  * LDS_STRIDE;
        const float4* it = reinterpret_cast<const float4*>(item_table + (long long)dst[i] * NF);
        float acc = 0.0f;
        #pragma unroll
        for (int q = 0; q < 8; ++q) {
            float4 iv = it[q];
            USER_DOT(acc, iv, t0, t1, t2, t3, t4, t5);
        }
        out[i] = acc;
    }
}

extern "C" void kernel_launch(void* const* d_in, const int* in_sizes, int n_in,
                              void* d_out, int out_size, void* d_ws, size_t ws_size,
                              hipStream_t stream) {
    const int* dow = (const int*)d_in[0];
    const int* tmi = (const int*)d_in[1];
    const int* sx  = (const int*)d_in[2];
    const int* ag  = (const int*)d_in[3];
    const int* mo  = (const int*)d_in[4];
    const int* dy  = (const int*)d_in[5];
    const int* dst = (const int*)d_in[6];
    const float* e_dow   = (const float*)d_in[7];
    const float* e_time  = (const float*)d_in[8];
    const float* e_sex   = (const float*)d_in[9];
    const float* e_age   = (const float*)d_in[10];
    const float* e_month = (const float*)d_in[11];
    const float* e_day   = (const float*)d_in[12];
    const float* W       = (const float*)d_in[13];
    const float* bvec    = (const float*)d_in[14];
    const float* item    = (const float*)d_in[15];
    float* out = (float*)d_out;
    const int n = in_sizes[0];

    // 4 rows/thread: 2048 blocks x 256 threads covers N=2,097,152 in one trip
    dim3 grid(2048), block(256);
    mf_kernel<<<grid, block, 0, stream>>>(dow, tmi, sx, ag, mo, dy, dst,
                                          e_dow, e_time, e_sex, e_age, e_month, e_day,
                                          W, bvec, item, out, n);
}

// Round 3
// 304.052 us; speedup vs baseline: 1.1160x; 1.1160x over previous
//
#include <hip/hip_runtime.h>

// MatrixFactorization: out[i] = dot(user_i, item_table[dest_i])
// user_i = b + sum_k emb_k[idx_k[i]] @ W_k  (W_k = rows [4k,4k+4) of W[24,32])
// Round 3: 2 rows/thread (int2 index loads, 2 independent item-gather chains),
// __launch_bounds__(256,4): VGPR cap 128 holds WITHOUT spills for the 2-row
// live set (round 2's 4-row version spilled 720 MB of scratch traffic).

#define NF 32
#define LDS_STRIDE 36           // floats per padded table row (144 B, 16B-aligned)
#define NV 176                  // 7+24+2+100+12+31 vocab entries

__device__ __forceinline__ float4 ldsf4(const float* p) {
    return *reinterpret_cast<const float4*>(p);
}

// acc += dot( sum of 6 LDS user quads , item quad )
#define USER_DOT(ACC, IV, B0, B1, B2, B3, B4, B5)                         \
    {                                                                     \
        float4 u0 = ldsf4(&proj[(B0) + q * 4]);                           \
        float4 u1 = ldsf4(&proj[(B1) + q * 4]);                           \
        float4 u2 = ldsf4(&proj[(B2) + q * 4]);                           \
        float4 u3 = ldsf4(&proj[(B3) + q * 4]);                           \
        float4 u4 = ldsf4(&proj[(B4) + q * 4]);                           \
        float4 u5 = ldsf4(&proj[(B5) + q * 4]);                           \
        float ux = u0.x + u1.x + u2.x + u3.x + u4.x + u5.x;               \
        float uy = u0.y + u1.y + u2.y + u3.y + u4.y + u5.y;               \
        float uz = u0.z + u1.z + u2.z + u3.z + u4.z + u5.z;               \
        float uw = u0.w + u1.w + u2.w + u3.w + u4.w + u5.w;               \
        ACC = fmaf(ux, (IV).x, ACC);                                      \
        ACC = fmaf(uy, (IV).y, ACC);                                      \
        ACC = fmaf(uz, (IV).z, ACC);                                      \
        ACC = fmaf(uw, (IV).w, ACC);                                      \
    }

__global__ __launch_bounds__(256, 4)
void mf_kernel(const int* __restrict__ dow, const int* __restrict__ tmi,
               const int* __restrict__ sx,  const int* __restrict__ ag,
               const int* __restrict__ mo,  const int* __restrict__ dy,
               const int* __restrict__ dst,
               const float* __restrict__ e_dow,   const float* __restrict__ e_time,
               const float* __restrict__ e_sex,   const float* __restrict__ e_age,
               const float* __restrict__ e_month, const float* __restrict__ e_day,
               const float* __restrict__ W, const float* __restrict__ bvec,
               const float* __restrict__ item_table,
               float* __restrict__ out, int n)
{
    __shared__ float proj[NV * LDS_STRIDE];   // 25,344 B

    // ---- Stage 1: build projected vocab tables in LDS ----
    const int tid = threadIdx.x;
    for (int t = tid; t < NV * NF; t += blockDim.x) {
        int entry = t >> 5;
        int f     = t & 31;
        int k, v;
        const float* e;
        if      (entry < 7)   { k = 0; v = entry;       e = e_dow;   }
        else if (entry < 31)  { k = 1; v = entry - 7;   e = e_time;  }
        else if (entry < 33)  { k = 2; v = entry - 31;  e = e_sex;   }
        else if (entry < 133) { k = 3; v = entry - 33;  e = e_age;   }
        else if (entry < 145) { k = 4; v = entry - 133; e = e_month; }
        else                  { k = 5; v = entry - 145; e = e_day;   }
        float acc = (k == 0) ? bvec[f] : 0.0f;
        #pragma unroll
        for (int d = 0; d < 4; ++d)
            acc += e[v * 4 + d] * W[(k * 4 + d) * NF + f];
        proj[entry * LDS_STRIDE + f] = acc;
    }
    __syncthreads();

    // ---- Stage 2: 2 rows per thread ----
    const int npair = n >> 1;
    const int tstride = gridDim.x * blockDim.x;
    for (int t = blockIdx.x * blockDim.x + tid; t < npair; t += tstride) {
        const int2 i0 = reinterpret_cast<const int2*>(dow)[t];
        const int2 i1 = reinterpret_cast<const int2*>(tmi)[t];
        const int2 i2 = reinterpret_cast<const int2*>(sx)[t];
        const int2 i3 = reinterpret_cast<const int2*>(ag)[t];
        const int2 i4 = reinterpret_cast<const int2*>(mo)[t];
        const int2 i5 = reinterpret_cast<const int2*>(dy)[t];
        const int2 id = reinterpret_cast<const int2*>(dst)[t];

        const int a0 = (0   + i0.x) * LDS_STRIDE, b0 = (0   + i0.y) * LDS_STRIDE;
        const int a1 = (7   + i1.x) * LDS_STRIDE, b1 = (7   + i1.y) * LDS_STRIDE;
        const int a2 = (31  + i2.x) * LDS_STRIDE, b2 = (31  + i2.y) * LDS_STRIDE;
        const int a3 = (33  + i3.x) * LDS_STRIDE, b3 = (33  + i3.y) * LDS_STRIDE;
        const int a4 = (133 + i4.x) * LDS_STRIDE, b4 = (133 + i4.y) * LDS_STRIDE;
        const int a5 = (145 + i5.x) * LDS_STRIDE, b5 = (145 + i5.y) * LDS_STRIDE;

        const float4* itA = reinterpret_cast<const float4*>(item_table + (long long)id.x * NF);
        const float4* itB = reinterpret_cast<const float4*>(item_table + (long long)id.y * NF);

        float accA = 0.0f, accB = 0.0f;
        #pragma unroll
        for (int q = 0; q < 8; ++q) {
            float4 ivA = itA[q];
            float4 ivB = itB[q];
            USER_DOT(accA, ivA, a0, a1, a2, a3, a4, a5);
            USER_DOT(accB, ivB, b0, b1, b2, b3, b4, b5);
        }
        float2 o; o.x = accA; o.y = accB;
        reinterpret_cast<float2*>(out)[t] = o;
    }

    // tail (n odd) — not taken for N=2M, kept for correctness
    const int tail_start = (n >> 1) << 1;
    const int gtid = blockIdx.x * blockDim.x + tid;
    for (int i = tail_start + gtid; i < n; i += tstride) {
        const int t0 = (0   + dow[i]) * LDS_STRIDE;
        const int t1 = (7   + tmi[i]) * LDS_STRIDE;
        const int t2 = (31  + sx[i])  * LDS_STRIDE;
        const int t3 = (33  + ag[i])  * LDS_STRIDE;
        const int t4 = (133 + mo[i])  * LDS_STRIDE;
        const int t5 = (145 + dy[i])  * LDS_STRIDE;
        const float4* it = reinterpret_cast<const float4*>(item_table + (long long)dst[i] * NF);
        float acc = 0.0f;
        #pragma unroll
        for (int q = 0; q < 8; ++q) {
            float4 iv = it[q];
            USER_DOT(acc, iv, t0, t1, t2, t3, t4, t5);
        }
        out[i] = acc;
    }
}

extern "C" void kernel_launch(void* const* d_in, const int* in_sizes, int n_in,
                              void* d_out, int out_size, void* d_ws, size_t ws_size,
                              hipStream_t stream) {
    const int* dow = (const int*)d_in[0];
    const int* tmi = (const int*)d_in[1];
    const int* sx  = (const int*)d_in[2];
    const int* ag  = (const int*)d_in[3];
    const int* mo  = (const int*)d_in[4];
    const int* dy  = (const int*)d_in[5];
    const int* dst = (const int*)d_in[6];
    const float* e_dow   = (const float*)d_in[7];
    const float* e_time  = (const float*)d_in[8];
    const float* e_sex   = (const float*)d_in[9];
    const float* e_age   = (const float*)d_in[10];
    const float* e_month = (const float*)d_in[11];
    const float* e_day   = (const float*)d_in[12];
    const float* W       = (const float*)d_in[13];
    const float* bvec    = (const float*)d_in[14];
    const float* item    = (const float*)d_in[15];
    float* out = (float*)d_out;
    const int n = in_sizes[0];

    // 2 rows/thread: 4096 blocks x 256 threads covers N=2,097,152 in one trip
    dim3 grid(4096), block(256);
    mf_kernel<<<grid, block, 0, stream>>>(dow, tmi, sx, ag, mo, dy, dst,
                                          e_dow, e_time, e_sex, e_age, e_month, e_day,
                                          W, bvec, item, out, n);
}